// Round 1
// baseline (77.762 us; speedup 1.0000x reference)
//
#include <hip/hip_runtime.h>
#include <stdint.h>

#define DIMS   1000
#define NLEV   10
#define NPIX   784
#define NBATCH 256
#define NCLS   10
#define WPD    32      // u32 words per dim-row (32*32 = 1024 >= 1000)
#define HALF   392     // pixels staged per LDS half

// ---------------------------------------------------------------------------
// Kernel 1: pack sign bits of position [784,1000] and value_table [10,1000]
// into u32 words along the dim axis.
// ws layout (u32): [0, 25088) = pos_bits[pixel][word], [25088, 25408) = vt_bits
// ---------------------------------------------------------------------------
__global__ void pack_bits(const float* __restrict__ position,
                          const float* __restrict__ value_table,
                          uint32_t* __restrict__ ws_bits) {
    int i = blockIdx.x * blockDim.x + threadIdx.x;
    const int n_pos = NPIX * WPD;
    const int n_tot = n_pos + NLEV * WPD;
    if (i >= n_tot) return;
    const float* src;
    int row, w;
    if (i < n_pos) { row = i >> 5; w = i & 31; src = position; }
    else           { int k = i - n_pos; row = k >> 5; w = k & 31; src = value_table; }

    uint32_t bits = 0;
    const float4* s4 = (const float4*)(src + row * DIMS + w * 32);  // 16B aligned
    #pragma unroll
    for (int c = 0; c < 8; ++c) {
        int d = w * 32 + c * 4;
        if (d < DIMS) {            // DIMS % 4 == 0 -> chunks never straddle
            float4 v = s4[c];
            bits |= (v.x > 0.f ? 1u : 0u) << (c * 4 + 0);
            bits |= (v.y > 0.f ? 1u : 0u) << (c * 4 + 1);
            bits |= (v.z > 0.f ? 1u : 0u) << (c * 4 + 2);
            bits |= (v.w > 0.f ? 1u : 0u) << (c * 4 + 3);
        }
    }
    ws_bits[i] = bits;
}

// ---------------------------------------------------------------------------
// Kernel 2: one block per batch element. Bit-sliced popcount of
// XNOR(pos_bit, vt_bit[idx]) per dim, hard-quantize, then logits = enc @ W^T.
// ---------------------------------------------------------------------------
__global__ __launch_bounds__(256) void hdc_main(const float* __restrict__ x,
                                                const float* __restrict__ W,
                                                const uint32_t* __restrict__ ws_bits,
                                                float* __restrict__ out) {
    __shared__ alignas(16) uint32_t s_pos[HALF * WPD];   // 50176 B
    __shared__ alignas(16) uint32_t s_vt[NLEV * WPD];    //  1280 B
    __shared__ uint32_t s_idx[NPIX];                     //  3136 B
    __shared__ uint32_t s_cnt[32 * 8 * 7];               //  7168 B
    __shared__ float    s_red[4][NCLS];                  //   160 B
    // total ~61.9 KB < 64 KB static LDS limit

    const int b = blockIdx.x;
    const int t = threadIdx.x;

    // --- per-pixel level index: idx = clip(rint(x*9), 0, 9) (rint = half-even, matches jnp.round)
    for (int p = t; p < NPIX; p += 256) {
        float v = x[b * NPIX + p] * 9.0f;
        int l = (int)rintf(v);
        l = l < 0 ? 0 : (l > 9 ? 9 : l);
        s_idx[p] = (uint32_t)l;
    }
    // --- stage vt bits (320 u32 = 80 uint4)
    {
        const uint4* src = (const uint4*)(ws_bits + NPIX * WPD);
        uint4* dst = (uint4*)s_vt;
        if (t < 80) dst[t] = src[t];
    }

    const int w = t & 31;   // dim word 0..31
    const int g = t >> 5;   // pixel group 0..7 (49 pixels per half each)
    uint32_t c0 = 0, c1 = 0, c2 = 0, c3 = 0, c4 = 0, c5 = 0, c6 = 0;

    #pragma unroll
    for (int h = 0; h < 2; ++h) {
        // stage this half of pos bits: 12544 u32 = 3136 uint4
        {
            const uint4* src = (const uint4*)(ws_bits + (size_t)h * HALF * WPD);
            uint4* dst = (uint4*)s_pos;
            for (int i = t; i < 3136; i += 256) dst[i] = src[i];
        }
        __syncthreads();
        // accumulate 49 pixels for this (w, g)
        const int pbase = g * 49;
        #pragma unroll 7
        for (int k = 0; k < 49; ++k) {
            int pl = pbase + k;
            uint32_t l = s_idx[h * HALF + pl];
            uint32_t bits = ~(s_pos[pl * WPD + w] ^ s_vt[l * WPD + w]);
            // ripple-add bit-plane into 7-plane counter (max 98 < 128)
            uint32_t carry = bits, tmp;
            tmp = c0 & carry; c0 ^= carry; carry = tmp;
            tmp = c1 & carry; c1 ^= carry; carry = tmp;
            tmp = c2 & carry; c2 ^= carry; carry = tmp;
            tmp = c3 & carry; c3 ^= carry; carry = tmp;
            tmp = c4 & carry; c4 ^= carry; carry = tmp;
            tmp = c5 & carry; c5 ^= carry; carry = tmp;
            c6 ^= carry;
        }
        __syncthreads();   // everyone done reading s_pos before next overwrite
    }

    // --- dump counters: layout s_cnt[(w*8+g)*7 + i]
    {
        int base = (w * 8 + g) * 7;
        s_cnt[base + 0] = c0; s_cnt[base + 1] = c1; s_cnt[base + 2] = c2;
        s_cnt[base + 3] = c3; s_cnt[base + 4] = c4; s_cnt[base + 5] = c5;
        s_cnt[base + 6] = c6;
    }
    __syncthreads();

    // --- epilogue: per-dim count -> enc(+-1) -> partial logits
    float partial[NCLS];
    #pragma unroll
    for (int c = 0; c < NCLS; ++c) partial[c] = 0.f;

    if (t < 250) {     // 250 threads x 4 dims = 1000
        float enc[4];
        #pragma unroll
        for (int j = 0; j < 4; ++j) {
            int d = 4 * t + j;
            int w2 = d >> 5, bit = d & 31;
            int cnt = 0;
            #pragma unroll
            for (int g2 = 0; g2 < 8; ++g2) {
                int base = (w2 * 8 + g2) * 7;
                #pragma unroll
                for (int i = 0; i < 7; ++i)
                    cnt += (int)((s_cnt[base + i] >> bit) & 1u) << i;
            }
            // s = 2*cnt - 784 ; enc = (s > 0) ? 1 : -1  <=>  cnt > 392
            enc[j] = (cnt > 392) ? 1.0f : -1.0f;
        }
        #pragma unroll
        for (int c = 0; c < NCLS; ++c) {
            const float4* wv = (const float4*)(W + c * DIMS + 4 * t);  // 16B aligned
            float4 wl = *wv;
            partial[c] = enc[0] * wl.x + enc[1] * wl.y + enc[2] * wl.z + enc[3] * wl.w;
        }
    }

    // --- wave (64-lane) shuffle reduction, then cross-wave via LDS
    #pragma unroll
    for (int c = 0; c < NCLS; ++c) {
        #pragma unroll
        for (int off = 32; off > 0; off >>= 1)
            partial[c] += __shfl_down(partial[c], off);
    }
    const int lane = t & 63, wid = t >> 6;
    if (lane == 0) {
        #pragma unroll
        for (int c = 0; c < NCLS; ++c) s_red[wid][c] = partial[c];
    }
    __syncthreads();
    if (t < NCLS)
        out[b * NCLS + t] = s_red[0][t] + s_red[1][t] + s_red[2][t] + s_red[3][t];
}

extern "C" void kernel_launch(void* const* d_in, const int* in_sizes, int n_in,
                              void* d_out, int out_size, void* d_ws, size_t ws_size,
                              hipStream_t stream) {
    const float* x        = (const float*)d_in[0];  // [256,28,28]
    const float* position = (const float*)d_in[1];  // [784,1000]
    const float* vtab     = (const float*)d_in[2];  // [10,1000]
    const float* W        = (const float*)d_in[3];  // [10,1000]
    float* out            = (float*)d_out;          // [256,10]
    uint32_t* ws_bits     = (uint32_t*)d_ws;        // 25408 u32 = ~102 KB

    const int n_words = NPIX * WPD + NLEV * WPD;    // 25408
    pack_bits<<<(n_words + 255) / 256, 256, 0, stream>>>(position, vtab, ws_bits);
    hdc_main<<<NBATCH, 256, 0, stream>>>(x, W, ws_bits, out);
}

// Round 2
// 74.934 us; speedup vs baseline: 1.0377x; 1.0377x over previous
//
#include <hip/hip_runtime.h>
#include <stdint.h>

#define DIMS   1000
#define NLEV   10
#define NPIX   784
#define NBATCH 256
#define NCLS   10
#define WPD    32      // u32 words per dim-row (32*32 = 1024 >= 1000)
#define QPIX   196     // pixels staged per LDS quarter
#define NGRP   16      // pixel groups (one per 32-lane half-wave)
#define NPLANE 6       // bit planes per counter (max 52 pixels/group < 64)

// ---------------------------------------------------------------------------
// Kernel 1: pack sign bits of position [784,1000] and value_table [10,1000]
// into u32 words along the dim axis.
// ws layout (u32): [0, 25088) = pos_bits[pixel][word], [25088, 25408) = vt_bits
// ---------------------------------------------------------------------------
__global__ void pack_bits(const float* __restrict__ position,
                          const float* __restrict__ value_table,
                          uint32_t* __restrict__ ws_bits) {
    int i = blockIdx.x * blockDim.x + threadIdx.x;
    const int n_pos = NPIX * WPD;
    const int n_tot = n_pos + NLEV * WPD;
    if (i >= n_tot) return;
    const float* src;
    int row, w;
    if (i < n_pos) { row = i >> 5; w = i & 31; src = position; }
    else           { int k = i - n_pos; row = k >> 5; w = k & 31; src = value_table; }

    uint32_t bits = 0;
    const float4* s4 = (const float4*)(src + row * DIMS + w * 32);  // 16B aligned
    #pragma unroll
    for (int c = 0; c < 8; ++c) {
        int d = w * 32 + c * 4;
        if (d < DIMS) {            // DIMS % 4 == 0 -> chunks never straddle
            float4 v = s4[c];
            bits |= (v.x > 0.f ? 1u : 0u) << (c * 4 + 0);
            bits |= (v.y > 0.f ? 1u : 0u) << (c * 4 + 1);
            bits |= (v.z > 0.f ? 1u : 0u) << (c * 4 + 2);
            bits |= (v.w > 0.f ? 1u : 0u) << (c * 4 + 3);
        }
    }
    ws_bits[i] = bits;
}

// ---------------------------------------------------------------------------
// Kernel 2: one block per batch element, 512 threads (8 waves/CU).
// Bit-sliced popcount of XNOR(pos_bit, vt_bit[idx]) per dim, hard-quantize,
// then logits = enc @ W^T.
// Pixel->group map: within each 196-pixel quarter, group g takes local pixels
// g + 16*j (j=0..11); groups 12..15 additionally take 192+(g-12).
// Totals: groups 0-11 -> 48 pixels, 12-15 -> 52 pixels (< 64 -> 6 planes).
// ---------------------------------------------------------------------------
__global__ __launch_bounds__(512) void hdc_main(const float* __restrict__ x,
                                                const float* __restrict__ W,
                                                const uint32_t* __restrict__ ws_bits,
                                                float* __restrict__ out) {
    __shared__ alignas(16) uint32_t s_pos[QPIX * WPD];        // 25088 B
    __shared__ alignas(16) uint32_t s_vt[NLEV * WPD];         //  1280 B
    __shared__ uint32_t s_idx[NPIX];                          //  3136 B
    __shared__ uint32_t s_cnt[WPD * NGRP * NPLANE];           // 12288 B
    __shared__ float    s_red[8][NCLS];                       //   320 B
    // total ~42 KB static LDS

    const int b = blockIdx.x;
    const int t = threadIdx.x;

    // --- per-pixel level index: idx = clip(rint(x*9), 0, 9) (rint = half-even, matches jnp.round)
    for (int p = t; p < NPIX; p += 512) {
        float v = x[b * NPIX + p] * 9.0f;
        int l = (int)rintf(v);
        l = l < 0 ? 0 : (l > 9 ? 9 : l);
        s_idx[p] = (uint32_t)l;
    }
    // --- stage vt bits (320 u32 = 80 uint4)
    {
        const uint4* src = (const uint4*)(ws_bits + NPIX * WPD);
        uint4* dst = (uint4*)s_vt;
        if (t < 80) dst[t] = src[t];
    }

    const int w = t & 31;   // dim word 0..31
    const int g = t >> 5;   // pixel group 0..15
    uint32_t c0 = 0, c1 = 0, c2 = 0, c3 = 0, c4 = 0, c5 = 0;

    #pragma unroll
    for (int q = 0; q < 4; ++q) {
        // stage quarter q of pos bits: 196*32 u32 = 1568 uint4
        {
            const uint4* src = (const uint4*)(ws_bits + (size_t)q * QPIX * WPD);
            uint4* dst = (uint4*)s_pos;
            for (int i = t; i < 1568; i += 512) dst[i] = src[i];
        }
        __syncthreads();
        const int npix = (g < 12) ? 12 : 13;
        #pragma unroll 4
        for (int k = 0; k < npix; ++k) {
            int pl = (k < 12) ? (g + 16 * k) : (192 + (g - 12));
            uint32_t l = s_idx[q * QPIX + pl];
            uint32_t bits = ~(s_pos[pl * WPD + w] ^ s_vt[l * WPD + w]);
            // ripple-add bit-plane into 6-plane counter (max 52 < 64)
            uint32_t carry = bits, tmp;
            tmp = c0 & carry; c0 ^= carry; carry = tmp;
            tmp = c1 & carry; c1 ^= carry; carry = tmp;
            tmp = c2 & carry; c2 ^= carry; carry = tmp;
            tmp = c3 & carry; c3 ^= carry; carry = tmp;
            tmp = c4 & carry; c4 ^= carry; carry = tmp;
            c5 ^= carry;
        }
        __syncthreads();   // everyone done reading s_pos before next overwrite
    }

    // --- dump counters: layout s_cnt[(w*NGRP+g)*NPLANE + i]
    {
        int base = (w * NGRP + g) * NPLANE;
        s_cnt[base + 0] = c0; s_cnt[base + 1] = c1; s_cnt[base + 2] = c2;
        s_cnt[base + 3] = c3; s_cnt[base + 4] = c4; s_cnt[base + 5] = c5;
    }
    __syncthreads();

    // --- epilogue: per-dim count -> enc(+-1) -> partial logits (2 dims/thread)
    float partial[NCLS];
    #pragma unroll
    for (int c = 0; c < NCLS; ++c) partial[c] = 0.f;

    if (t < 500) {     // 500 threads x 2 dims = 1000
        float enc[2];
        #pragma unroll
        for (int j = 0; j < 2; ++j) {
            int d = 2 * t + j;
            int w2 = d >> 5, bit = d & 31;
            int cnt = 0;
            #pragma unroll
            for (int g2 = 0; g2 < NGRP; ++g2) {
                int base = (w2 * NGRP + g2) * NPLANE;
                #pragma unroll
                for (int i = 0; i < NPLANE; ++i)
                    cnt += (int)((s_cnt[base + i] >> bit) & 1u) << i;
            }
            // s = 2*cnt - 784 ; enc = (s > 0) ? 1 : -1  <=>  cnt > 392
            enc[j] = (cnt > 392) ? 1.0f : -1.0f;
        }
        #pragma unroll
        for (int c = 0; c < NCLS; ++c) {
            const float2* wv = (const float2*)(W + c * DIMS + 2 * t);  // 8B aligned
            float2 wl = *wv;
            partial[c] = enc[0] * wl.x + enc[1] * wl.y;
        }
    }

    // --- wave (64-lane) shuffle reduction, then cross-wave via LDS
    #pragma unroll
    for (int c = 0; c < NCLS; ++c) {
        #pragma unroll
        for (int off = 32; off > 0; off >>= 1)
            partial[c] += __shfl_down(partial[c], off);
    }
    const int lane = t & 63, wid = t >> 6;
    if (lane == 0) {
        #pragma unroll
        for (int c = 0; c < NCLS; ++c) s_red[wid][c] = partial[c];
    }
    __syncthreads();
    if (t < NCLS) {
        float acc = 0.f;
        #pragma unroll
        for (int v = 0; v < 8; ++v) acc += s_red[v][t];
        out[b * NCLS + t] = acc;
    }
}

extern "C" void kernel_launch(void* const* d_in, const int* in_sizes, int n_in,
                              void* d_out, int out_size, void* d_ws, size_t ws_size,
                              hipStream_t stream) {
    const float* x        = (const float*)d_in[0];  // [256,28,28]
    const float* position = (const float*)d_in[1];  // [784,1000]
    const float* vtab     = (const float*)d_in[2];  // [10,1000]
    const float* W        = (const float*)d_in[3];  // [10,1000]
    float* out            = (float*)d_out;          // [256,10]
    uint32_t* ws_bits     = (uint32_t*)d_ws;        // 25408 u32 = ~102 KB

    const int n_words = NPIX * WPD + NLEV * WPD;    // 25408
    pack_bits<<<(n_words + 255) / 256, 256, 0, stream>>>(position, vtab, ws_bits);
    hdc_main<<<NBATCH, 512, 0, stream>>>(x, W, ws_bits, out);
}

// Round 3
// 72.241 us; speedup vs baseline: 1.0764x; 1.0373x over previous
//
#include <hip/hip_runtime.h>
#include <stdint.h>

#define DIMS   1000
#define NLEV   10
#define NPIX   784
#define NBATCH 256
#define NCLS   10
#define WPD    32      // u32 words per dim-row (32*32 = 1024 >= 1000)

// ---------------------------------------------------------------------------
// Kernel 1: ballot-pack sign bits. One wave per row; 64 lanes load 64
// consecutive floats (coalesced), __ballot forms 64 bits -> one u64 store.
// Rows 0..783 = position, 784..793 = value_table (contiguous in ws).
// ---------------------------------------------------------------------------
__global__ __launch_bounds__(256) void pack_ballot(const float* __restrict__ position,
                                                   const float* __restrict__ value_table,
                                                   uint64_t* __restrict__ ws64) {
    const int t    = threadIdx.x;
    const int lane = t & 63;
    const int wv   = (blockIdx.x * 256 + t) >> 6;
    const int nw   = (gridDim.x * 256) >> 6;
    for (int r = wv; r < NPIX + NLEV; r += nw) {
        const float* src = (r < NPIX) ? (position + (size_t)r * DIMS)
                                      : (value_table + (size_t)(r - NPIX) * DIMS);
        #pragma unroll
        for (int k = 0; k < 16; ++k) {           // 16*64 = 1024 >= 1000
            int d = k * 64 + lane;
            float v = (d < DIMS) ? src[d] : 0.f; // pad bits -> 0 (harmless)
            uint64_t m = __ballot(v > 0.f);
            if (lane == 0) ws64[(size_t)r * 16 + k] = m;
        }
    }
}

// full adder on bit-planes: sum/carry of a+b+cin (5 ops)
__device__ __forceinline__ void fa(uint32_t a, uint32_t b, uint32_t cin,
                                   uint32_t& s, uint32_t& c) {
    uint32_t t = a ^ b;
    s = t ^ cin;
    c = (a & b) | (t & cin);
}

// ---------------------------------------------------------------------------
// Kernel 2: one block per batch element, 512 threads.
// lane role: w = t&31 (dim word), g = t>>5 (pixel group, 16 groups x 49 pix).
// Count per-dim MISMATCH bits (pos^vt) with a CSA tree into 6 bit-planes,
// merge groups via bit-sliced adds, threshold bitwise, then tiny logit GEMV.
// ---------------------------------------------------------------------------
__global__ __launch_bounds__(512) void hdc_main(const float* __restrict__ x,
                                                const float* __restrict__ W,
                                                const uint32_t* __restrict__ ws_bits,
                                                float* __restrict__ out) {
    __shared__ uint32_t s_idx[NPIX];             // 3136 B
    __shared__ uint32_t s_vt[NLEV * WPD];        // 1280 B
    __shared__ uint32_t s_cnt1[32 * 8 * 7];      // 7168 B (8 merged groups x 7 planes)
    __shared__ uint32_t s_cnt2[32 * 4 * 8];      // 4096 B
    __shared__ uint32_t s_cnt3[32 * 2 * 9];      // 2304 B
    __shared__ uint32_t s_cnt4_enc[32];          //  128 B (enc bits per word)
    __shared__ float    s_red[8][NCLS];          //  320 B

    const int b = blockIdx.x;
    const int t = threadIdx.x;

    // --- per-pixel level index: idx = clip(rint(x*9), 0, 9)
    for (int p = t; p < NPIX; p += 512) {
        float v = x[b * NPIX + p] * 9.0f;
        int l = (int)rintf(v);                   // half-even, matches jnp.round
        l = l < 0 ? 0 : (l > 9 ? 9 : l);
        s_idx[p] = (uint32_t)(l * WPD);          // pre-scaled row offset
    }
    if (t < NLEV * WPD) s_vt[t] = ws_bits[NPIX * WPD + t];
    __syncthreads();

    const int w = t & 31;
    const int g = t >> 5;

    uint32_t p0 = 0, p1 = 0, p2 = 0, p3 = 0, p4 = 0, p5 = 0;

    // pixels for group g: pl = g + 16*k, k = 0..48  (49 pixels, 6 chunks of 8 + 1)
    for (int c = 0; c < 6; ++c) {
        uint32_t idxv[8], posv[8], xv[8];
        #pragma unroll
        for (int j = 0; j < 8; ++j)
            idxv[j] = s_idx[g + 128 * c + 16 * j];
        #pragma unroll
        for (int j = 0; j < 8; ++j)
            posv[j] = ws_bits[(g + 128 * c + 16 * j) * WPD + w];   // global, L2
        #pragma unroll
        for (int j = 0; j < 8; ++j)
            xv[j] = posv[j] ^ s_vt[idxv[j] + w];                   // mismatch bits
        // CSA tree: 8 inputs -> planes
        uint32_t sa, ca, sb, cb, sc, cc, sd, cd, se, ce, sf, cf, cg;
        fa(xv[0], xv[1], xv[2], sa, ca);
        fa(xv[3], xv[4], xv[5], sb, cb);
        fa(xv[6], xv[7], p0,   sc, cc);
        fa(sa, sb, sc, p0, cd);          // new ones plane
        fa(ca, cb, cc, se, ce);
        fa(se, cd, p1, p1, cf);          // new twos plane
        fa(ce, cf, p2, p2, cg);          // new fours plane
        uint32_t tmp = p3 & cg; p3 ^= cg;          // ripple weight-8 carry
        uint32_t tm2 = p4 & tmp; p4 ^= tmp;
        p5 ^= tm2;
    }
    {   // tail pixel: pl = g + 768
        uint32_t xb = ws_bits[(g + 768) * WPD + w] ^ s_vt[s_idx[g + 768] + w];
        uint32_t c = xb, tmp;
        tmp = p0 & c; p0 ^= c; c = tmp;
        tmp = p1 & c; p1 ^= c; c = tmp;
        tmp = p2 & c; p2 ^= c; c = tmp;
        tmp = p3 & c; p3 ^= c; c = tmp;
        tmp = p4 & c; p4 ^= c; c = tmp;
        p5 ^= c;
    }

    // --- merge the wave's two groups via shuffle: lanes 0..31 get g, 32..63 hold g+1
    {
        uint32_t q0 = __shfl_down(p0, 32), q1 = __shfl_down(p1, 32),
                 q2 = __shfl_down(p2, 32), q3 = __shfl_down(p3, 32),
                 q4 = __shfl_down(p4, 32), q5 = __shfl_down(p5, 32);
        // 6-plane + 6-plane -> 7-plane bit-sliced add (lanes<32 meaningful)
        uint32_t r0, r1, r2, r3, r4, r5, r6, c, tt;
        c  = p0 & q0; r0 = p0 ^ q0;
        tt = p1 ^ q1; r1 = tt ^ c; c = (p1 & q1) | (tt & c);
        tt = p2 ^ q2; r2 = tt ^ c; c = (p2 & q2) | (tt & c);
        tt = p3 ^ q3; r3 = tt ^ c; c = (p3 & q3) | (tt & c);
        tt = p4 ^ q4; r4 = tt ^ c; c = (p4 & q4) | (tt & c);
        tt = p5 ^ q5; r5 = tt ^ c; c = (p5 & q5) | (tt & c);
        r6 = c;
        const int wid = t >> 6;                 // merged group 0..7
        if ((t & 63) < 32) {
            int base = (w * 8 + wid) * 7;
            s_cnt1[base + 0] = r0; s_cnt1[base + 1] = r1; s_cnt1[base + 2] = r2;
            s_cnt1[base + 3] = r3; s_cnt1[base + 4] = r4; s_cnt1[base + 5] = r5;
            s_cnt1[base + 6] = r6;
        }
    }
    __syncthreads();

    // --- tree round 2: 8 -> 4 groups (7 -> 8 planes), 128 threads
    if (t < 128) {
        int w2 = t & 31, j = t >> 5;
        int ba = (w2 * 8 + 2 * j) * 7, bb = (w2 * 8 + 2 * j + 1) * 7;
        uint32_t c = 0, tt;
        int bo = (w2 * 4 + j) * 8;
        #pragma unroll
        for (int i = 0; i < 7; ++i) {
            uint32_t a = s_cnt1[ba + i], bv = s_cnt1[bb + i];
            tt = a ^ bv; s_cnt2[bo + i] = tt ^ c; c = (a & bv) | (tt & c);
        }
        s_cnt2[bo + 7] = c;
    }
    __syncthreads();

    // --- tree round 3: 4 -> 2 groups (8 -> 9 planes), 64 threads
    if (t < 64) {
        int w2 = t & 31, j = t >> 5;
        int ba = (w2 * 4 + 2 * j) * 8, bb = (w2 * 4 + 2 * j + 1) * 8;
        uint32_t c = 0, tt;
        int bo = (w2 * 2 + j) * 9;
        #pragma unroll
        for (int i = 0; i < 8; ++i) {
            uint32_t a = s_cnt2[ba + i], bv = s_cnt2[bb + i];
            tt = a ^ bv; s_cnt3[bo + i] = tt ^ c; c = (a & bv) | (tt & c);
        }
        s_cnt3[bo + 8] = c;
    }
    __syncthreads();

    // --- final merge + bitwise threshold, 32 threads
    // m[d] = mismatch count; enc = +1 iff matches > 392 iff m <= 391
    // carry-out of (m + 632) over 10 bits == (m >= 392); enc = ~carry
    if (t < 32) {
        int ba = (t * 2) * 9, bb = (t * 2 + 1) * 9;
        uint32_t cnt[10];
        uint32_t c = 0, tt;
        #pragma unroll
        for (int i = 0; i < 9; ++i) {
            uint32_t a = s_cnt3[ba + i], bv = s_cnt3[bb + i];
            tt = a ^ bv; cnt[i] = tt ^ c; c = (a & bv) | (tt & c);
        }
        cnt[9] = c;
        // 632 = 0b1001111000 : bits 3,4,5,6,9 set
        uint32_t cy = 0;                      // bits 0..2: k=0 -> cy stays 0
        cy = cnt[3];                          // k=1, cy was 0 -> maj = a
        cy = cnt[4] | cy;                     // k=1
        cy = cnt[5] | cy;                     // k=1
        cy = cnt[6] | cy;                     // k=1
        cy = cnt[7] & cy;                     // k=0
        cy = cnt[8] & cy;                     // k=0
        cy = cnt[9] | cy;                     // k=1
        s_cnt4_enc[t] = ~cy;                  // enc bit = 1 -> +1
    }
    __syncthreads();

    // --- logits: 500 threads x 2 dims, +-W accumulate, shuffle reduce
    float partial[NCLS];
    #pragma unroll
    for (int cc = 0; cc < NCLS; ++cc) partial[cc] = 0.f;

    if (t < 500) {
        int d0 = 2 * t;
        uint32_t ew = s_cnt4_enc[d0 >> 5];
        float e0 = ((ew >> (d0 & 31)) & 1u) ? 1.0f : -1.0f;
        float e1 = ((ew >> ((d0 + 1) & 31)) & 1u) ? 1.0f : -1.0f;  // d0,d0+1 same word (d0 even)
        #pragma unroll
        for (int cc = 0; cc < NCLS; ++cc) {
            const float2* wv = (const float2*)(W + cc * DIMS + d0);
            float2 wl = *wv;
            partial[cc] = e0 * wl.x + e1 * wl.y;
        }
    }
    #pragma unroll
    for (int cc = 0; cc < NCLS; ++cc) {
        #pragma unroll
        for (int off = 32; off > 0; off >>= 1)
            partial[cc] += __shfl_down(partial[cc], off);
    }
    const int lane = t & 63, wid = t >> 6;
    if (lane == 0) {
        #pragma unroll
        for (int cc = 0; cc < NCLS; ++cc) s_red[wid][cc] = partial[cc];
    }
    __syncthreads();
    if (t < NCLS) {
        float acc = 0.f;
        #pragma unroll
        for (int v = 0; v < 8; ++v) acc += s_red[v][t];
        out[b * NCLS + t] = acc;
    }
}

extern "C" void kernel_launch(void* const* d_in, const int* in_sizes, int n_in,
                              void* d_out, int out_size, void* d_ws, size_t ws_size,
                              hipStream_t stream) {
    const float* x        = (const float*)d_in[0];  // [256,28,28]
    const float* position = (const float*)d_in[1];  // [784,1000]
    const float* vtab     = (const float*)d_in[2];  // [10,1000]
    const float* W        = (const float*)d_in[3];  // [10,1000]
    float* out            = (float*)d_out;          // [256,10]

    pack_ballot<<<200, 256, 0, stream>>>(position, vtab, (uint64_t*)d_ws);
    hdc_main<<<NBATCH, 512, 0, stream>>>(x, W, (const uint32_t*)d_ws, out);
}